// Round 1
// baseline (166.408 us; speedup 1.0000x reference)
//
#include <hip/hip_runtime.h>
#include <math.h>

#define BD 64
#define ND 200
#define CD 8
#define HD 256
#define WD 256
#define NBOX (BD * ND)      // 12800
#define NBLK (NBOX / 256)   // 50

__device__ __forceinline__ float softplus_f(float x) {
    // matches jax.nn.softplus: max(x,0) + log1p(exp(-|x|))
    return fmaxf(x, 0.0f) + log1pf(expf(-fabsf(x)));
}

__global__ __launch_bounds__(256) void yolo_partial(const float* __restrict__ pred,
                                                    const float* __restrict__ targets,
                                                    float* __restrict__ partial) {
    const int tid = blockIdx.x * 256 + threadIdx.x;  // box index, exactly NBOX threads
    const int b = tid / ND;

    const float* t = targets + (size_t)tid * 5;
    const float cls_id = t[0];
    const float c0 = t[1], c1 = t[2], c2 = t[3], c3 = t[4];

    const bool valid = (cls_id >= 0.0f) && ((c0 + c1 + c2 + c3) > 0.0f);
    const int xpix = (int)(c0 * (float)WD);   // trunc-toward-zero == jnp astype(int32) (positive)
    const int ypix = (int)(c1 * (float)HD);
    const bool inb = (xpix >= 0) && (xpix < WD) && (ypix >= 0) && (ypix < HD);
    const bool m = valid && inb;

    float bbox = 0.0f, obj = 0.0f, clsl = 0.0f;
    if (m) {
        const int xs = min(max(xpix, 0), WD - 1);
        const int ys = min(max(ypix, 0), HD - 1);
        const float* pb = pred + (size_t)b * CD * HD * WD + (size_t)ys * WD + xs;
        float p[8];
#pragma unroll
        for (int c = 0; c < 8; ++c) p[c] = pb[(size_t)c * (HD * WD)];  // 8 independent gathers in flight

        const float d0 = p[0] - c0, d1 = p[1] - c1, d2 = p[2] - c2, d3 = p[3] - c3;
        bbox = 0.25f * (d0 * d0 + d1 * d1 + d2 * d2 + d3 * d3);
        obj = softplus_f(p[4]) - p[4];  // z = 1

        const int ci = (int)fmaxf(cls_id, 0.0f);  // clip(cls_id, 0) -> int
        float s = 0.0f;
#pragma unroll
        for (int k = 0; k < 3; ++k) {
            const float z = (k == ci) ? 1.0f : 0.0f;
            s += softplus_f(p[5 + k]) - p[5 + k] * z;
        }
        clsl = s * (1.0f / 3.0f);
    }

    // wave(64)-level reduction of the three sums
#pragma unroll
    for (int off = 32; off > 0; off >>= 1) {
        bbox += __shfl_down(bbox, off, 64);
        obj  += __shfl_down(obj,  off, 64);
        clsl += __shfl_down(clsl, off, 64);
    }

    __shared__ float sb[4], so[4], sc[4];
    const int wave = threadIdx.x >> 6;
    const int lane = threadIdx.x & 63;
    if (lane == 0) { sb[wave] = bbox; so[wave] = obj; sc[wave] = clsl; }
    __syncthreads();

    if (threadIdx.x == 0) {
        partial[blockIdx.x * 3 + 0] = sb[0] + sb[1] + sb[2] + sb[3];
        partial[blockIdx.x * 3 + 1] = so[0] + so[1] + so[2] + so[3];
        partial[blockIdx.x * 3 + 2] = sc[0] + sc[1] + sc[2] + sc[3];
    }
}

__global__ __launch_bounds__(64) void yolo_final(const float* __restrict__ partial,
                                                 float* __restrict__ out) {
    const int t = threadIdx.x;
    float tb = 0.0f, to = 0.0f, tc = 0.0f;
    if (t < NBLK) {
        tb = partial[t * 3 + 0];
        to = partial[t * 3 + 1];
        tc = partial[t * 3 + 2];
    }
#pragma unroll
    for (int off = 32; off > 0; off >>= 1) {
        tb += __shfl_down(tb, off, 64);
        to += __shfl_down(to, off, 64);
        tc += __shfl_down(tc, off, 64);
    }
    if (t == 0) {
        out[0] = 0.05f * tb + 1.0f * to + 0.5f * tc;
        out[1] = tb;
        out[2] = to;
        out[3] = tc;
    }
}

extern "C" void kernel_launch(void* const* d_in, const int* in_sizes, int n_in,
                              void* d_out, int out_size, void* d_ws, size_t ws_size,
                              hipStream_t stream) {
    const float* pred    = (const float*)d_in[0];
    const float* targets = (const float*)d_in[1];
    float* out     = (float*)d_out;
    float* partial = (float*)d_ws;  // NBLK*3 floats, fully overwritten every call

    yolo_partial<<<NBLK, 256, 0, stream>>>(pred, targets, partial);
    yolo_final<<<1, 64, 0, stream>>>(partial, out);
}

// Round 2
// 164.715 us; speedup vs baseline: 1.0103x; 1.0103x over previous
//
#include <hip/hip_runtime.h>
#include <math.h>

#define BD 64
#define ND 200
#define CD 8
#define HD 256
#define WD 256
#define HW (HD * WD)
#define NBOX (BD * ND)          // 12800
#define NTHR (NBOX * CD)        // 102400, one thread per (box, channel)
#define NBLK (NTHR / 256)       // 400

__device__ __forceinline__ float softplus_f(float x) {
    // matches jax.nn.softplus: max(x,0) + log1p(exp(-|x|))
    return fmaxf(x, 0.0f) + log1pf(expf(-fabsf(x)));
}

__global__ __launch_bounds__(256) void yolo_partial(const float* __restrict__ pred,
                                                    const float* __restrict__ targets,
                                                    float* __restrict__ partial) {
    const int tid = blockIdx.x * 256 + threadIdx.x;   // (box, channel) index
    const int box = tid >> 3;
    const int c   = tid & 7;
    const int b   = box / ND;

    const float* t = targets + (size_t)box * 5;
    const float cls_id = t[0];
    const float c0 = t[1], c1 = t[2], c2 = t[3], c3 = t[4];

    const bool valid = (cls_id >= 0.0f) && ((c0 + c1 + c2 + c3) > 0.0f);
    const int xpix = (int)(c0 * (float)WD);   // trunc == jnp astype(int32) for positive values
    const int ypix = (int)(c1 * (float)HD);
    const bool inb = (xpix >= 0) && (xpix < WD) && (ypix >= 0) && (ypix < HD);
    const bool m = valid && inb;

    float bbox = 0.0f, obj = 0.0f, clsl = 0.0f;
    if (m) {
        const int xs = min(max(xpix, 0), WD - 1);
        const int ys = min(max(ypix, 0), HD - 1);
        const float p = pred[(size_t)b * CD * HW + (size_t)c * HW + (size_t)ys * WD + xs];

        if (c < 4) {
            const float tc = (c == 0) ? c0 : (c == 1) ? c1 : (c == 2) ? c2 : c3;
            const float d = p - tc;
            bbox = 0.25f * d * d;
        } else if (c == 4) {
            obj = softplus_f(p) - p;                 // z = 1
        } else {
            const int ci = (int)fmaxf(cls_id, 0.0f); // clip(cls_id, 0) -> int
            const float z = ((c - 5) == ci) ? 1.0f : 0.0f;
            clsl = (softplus_f(p) - p * z) * (1.0f / 3.0f);
        }
    }

    // wave(64)-level reduction of the three sums
#pragma unroll
    for (int off = 32; off > 0; off >>= 1) {
        bbox += __shfl_down(bbox, off, 64);
        obj  += __shfl_down(obj,  off, 64);
        clsl += __shfl_down(clsl, off, 64);
    }

    __shared__ float sb[4], so[4], sc[4];
    const int wave = threadIdx.x >> 6;
    const int lane = threadIdx.x & 63;
    if (lane == 0) { sb[wave] = bbox; so[wave] = obj; sc[wave] = clsl; }
    __syncthreads();

    if (threadIdx.x == 0) {
        partial[blockIdx.x * 3 + 0] = sb[0] + sb[1] + sb[2] + sb[3];
        partial[blockIdx.x * 3 + 1] = so[0] + so[1] + so[2] + so[3];
        partial[blockIdx.x * 3 + 2] = sc[0] + sc[1] + sc[2] + sc[3];
    }
}

__global__ __launch_bounds__(256) void yolo_final(const float* __restrict__ partial,
                                                  float* __restrict__ out) {
    const int t = threadIdx.x;
    float tb = 0.0f, to = 0.0f, tc = 0.0f;
    for (int i = t; i < NBLK; i += 256) {
        tb += partial[i * 3 + 0];
        to += partial[i * 3 + 1];
        tc += partial[i * 3 + 2];
    }
#pragma unroll
    for (int off = 32; off > 0; off >>= 1) {
        tb += __shfl_down(tb, off, 64);
        to += __shfl_down(to, off, 64);
        tc += __shfl_down(tc, off, 64);
    }
    __shared__ float sb[4], so[4], sc[4];
    const int wave = t >> 6;
    const int lane = t & 63;
    if (lane == 0) { sb[wave] = tb; so[wave] = to; sc[wave] = tc; }
    __syncthreads();

    if (t == 0) {
        const float B = sb[0] + sb[1] + sb[2] + sb[3];
        const float O = so[0] + so[1] + so[2] + so[3];
        const float C = sc[0] + sc[1] + sc[2] + sc[3];
        out[0] = 0.05f * B + 1.0f * O + 0.5f * C;
        out[1] = B;
        out[2] = O;
        out[3] = C;
    }
}

extern "C" void kernel_launch(void* const* d_in, const int* in_sizes, int n_in,
                              void* d_out, int out_size, void* d_ws, size_t ws_size,
                              hipStream_t stream) {
    const float* pred    = (const float*)d_in[0];
    const float* targets = (const float*)d_in[1];
    float* out     = (float*)d_out;
    float* partial = (float*)d_ws;  // NBLK*3 floats, fully overwritten every call

    yolo_partial<<<NBLK, 256, 0, stream>>>(pred, targets, partial);
    yolo_final<<<1, 256, 0, stream>>>(partial, out);
}